// Round 2
// baseline (321.138 us; speedup 1.0000x reference)
//
#include <hip/hip_runtime.h>
#include <math.h>

typedef unsigned short ushort_t;
typedef __attribute__((ext_vector_type(8))) short bf16x8;
typedef __attribute__((ext_vector_type(4))) float f32x4;
typedef __attribute__((ext_vector_type(8))) unsigned short u16x8;
typedef __attribute__((ext_vector_type(2))) unsigned int u32x2;
typedef __attribute__((ext_vector_type(4))) unsigned int u32x4;

#define N_TOK 65536
#define DIN 128
#define HD 256
#define DOUT 128
#define NEXP 8
#define MT 64
#define NB_T 320   /* tile-blocks per expert; grid-stride covers overflow */

__device__ __forceinline__ unsigned short f2bf(float f) {
    union { float f; unsigned int i; } v; v.f = f;
    unsigned int i = v.i;
    return (unsigned short)((i + 0x7FFFu + ((i >> 16) & 1u)) >> 16); // RNE
}

#define RT_BLOCK 1024
#define RT_TPB 128   /* tokens per block */

// ---------------------------------------------------------------------------
// Fused router + weight-pack + out-init.
//  - 128 tokens/block (halves the global-atomic phases vs 64/block).
//  - counts[] padded to 32 ints (128B) apart: the 8 per-block atomicAdds hit
//    8 different L2 lines instead of serializing on one.
//  - blocks 0..99 pack W1/W2/Wo into bf16 fragment order (chunk map
//    unchanged; by duality these serve as A-frags of W^T for the swapped
//    GEMMs and B-frags of Wo for GEMM3).
// ---------------------------------------------------------------------------
__global__ __launch_bounds__(RT_BLOCK)
void router_kernel(const float* __restrict__ x,
                   const float* __restrict__ Wg,
                   const float* __restrict__ W1,
                   const float* __restrict__ W2,
                   const float* __restrict__ Wo,
                   const float* __restrict__ bo,
                   int* __restrict__ counts,
                   int* __restrict__ list_tok,
                   float* __restrict__ list_w,
                   ushort_t* __restrict__ wt1f,
                   ushort_t* __restrict__ wt2f,
                   ushort_t* __restrict__ wotf,
                   float* __restrict__ out) {
    __shared__ float wgsT[NEXP * 132]; // padded leading dim: conflict-free b128
    __shared__ int lcnt[NEXP];
    __shared__ int lbase[NEXP];
    int tid = threadIdx.x;
    if (tid < NEXP) lcnt[tid] = 0;
    if (tid < DIN * NEXP) {
        int ee = tid & 7, k = tid >> 3;   // Wg[k][e]
        wgsT[ee * 132 + k] = Wg[tid];
    }
    // fused init_out: this block's 128 tokens
    {
        const float4* bo4 = (const float4*)bo;
        float4* ob = (float4*)(out + (size_t)blockIdx.x * RT_TPB * DOUT);
#pragma unroll
        for (int i = 0; i < 4; i++) {
            int idx = i * RT_BLOCK + tid;       // 0..4095
            ob[idx] = bo4[idx & 31];
        }
    }
    // fused pack_weights: 100 blocks x 1024 threads = 102400 chunks
    if (blockIdx.x < 100) {
        int id = blockIdx.x * RT_BLOCK + tid;
        const float* src; ushort_t* dst; int Nn, ksteps, c;
        if (id < 32768) {            // W1
            int ee = id >> 12; c = id & 4095;
            Nn = HD; ksteps = 4; src = W1 + (size_t)ee * DIN * HD; dst = wt1f + (size_t)id * 8;
        } else if (id < 98304) {     // W2
            int t = id - 32768; int ee = t >> 13; c = t & 8191;
            Nn = HD; ksteps = 8; src = W2 + (size_t)ee * HD * HD; dst = wt2f + (size_t)t * 8;
        } else {                     // Wo
            int t = id - 98304; c = t;
            Nn = DOUT; ksteps = 8; src = Wo; dst = wotf + (size_t)t * 8;
        }
        int L = c & 63; int kc = c >> 6;
        int kstep = kc % ksteps; int ntile = kc / ksteps;
        int qq = L >> 4, mm = L & 15;
        int n = ntile * 16 + mm; int k0 = kstep * 32 + qq * 8;
        u16x8 v;
#pragma unroll
        for (int j = 0; j < 8; j++) v[j] = f2bf(src[(size_t)(k0 + j) * Nn + n]);
        *(u16x8*)dst = v;
    }
    __syncthreads();

    int e = tid & 7;
    int tl = tid >> 3;
    int n = blockIdx.x * RT_TPB + tl;
    const float4* xr = (const float4*)(x + (size_t)n * DIN);
    const float4* wv4 = (const float4*)(wgsT + e * 132);
    float lg = 0.f;
#pragma unroll
    for (int kk = 0; kk < 32; kk++) {
        float4 xv = xr[kk];
        float4 wv = wv4[kk];
        lg += xv.x * wv.x;
        lg += xv.y * wv.y;
        lg += xv.z * wv.z;
        lg += xv.w * wv.w;
    }
    // top-1 over the 8 lanes of this token (ties -> lowest expert index)
    float v0 = lg; int e0 = e;
#pragma unroll
    for (int d = 1; d < 8; d <<= 1) {
        float ov = __shfl_xor(v0, d, 64);
        int oe = __shfl_xor(e0, d, 64);
        if (ov > v0 || (ov == v0 && oe < e0)) { v0 = ov; e0 = oe; }
    }
    // top-2: mask out e0, reduce again
    float mv = (e == e0) ? -3.0e38f : lg;
    float v1 = mv; int e1 = e;
#pragma unroll
    for (int d = 1; d < 8; d <<= 1) {
        float ov = __shfl_xor(v1, d, 64);
        int oe = __shfl_xor(e1, d, 64);
        if (ov > v1 || (ov == v1 && oe < e1)) { v1 = ov; e1 = oe; }
    }
    float t = expf(v1 - v0);
    float inv = 1.0f / (1.0f + t);
    float w0 = inv, w1 = t * inv;

    bool writer = (e == 0);
    int p0 = 0, p1 = 0;
    if (writer) {
        p0 = atomicAdd(&lcnt[e0], 1);
        p1 = atomicAdd(&lcnt[e1], 1);
    }
    __syncthreads();
    if (tid < NEXP) lbase[tid] = atomicAdd(&counts[tid * 32], lcnt[tid]);
    __syncthreads();
    if (writer) {
        int q0 = lbase[e0] + p0;
        list_tok[e0 * N_TOK + q0] = n;
        list_w[e0 * N_TOK + q0] = w0;
        int q1 = lbase[e1] + p1;
        list_tok[e1 * N_TOK + q1] = n;
        list_w[e1 * N_TOK + q1] = w1;
    }
}

// ---------------------------------------------------------------------------
// Fused per-expert MLP over 64-token tiles, SWAPPED-GEMM form:
//   GEMM1: h1^T = W1^T @ x^T   (A = wt1f pack, B = x chunks in LDS)
//   GEMM2: h2^T = W2^T @ h1^T  (A = wt2f pack, B = h1 chunks in LDS)
//   GEMM3: y    = h2  @ Wo     (A = h2 chunks in LDS, B = wotf pack)
// The single LDS chunk layout serves all three:
//   chunk(ks,tt,lane=q*16+m) = 8 bf16 of {token tt*16+m, idx ks*32+q*8..+7}
// Swapped C-frags hold 4 consecutive h-indices at a fixed token, so the
// epilogues are 2x v_cvt_pk_bf16_f32 + one contiguous ds_write_b64 (no
// transpose, no tr_read). All LDS reads are wave-contiguous ds_read_b128.
// x tile is staged into the same 32KB buffer (x dead after GEMM1; one extra
// barrier) -> LDS 33.3KB -> 4 blocks/CU. Weight loads pipelined 1 kstep.
// Grid-stride over tiles: 8 experts x 320 blocks.
// ---------------------------------------------------------------------------
__global__ __launch_bounds__(256, 4)
void expert_kernel(const float* __restrict__ x,
                   const int* __restrict__ counts,
                   const int* __restrict__ list_tok,
                   const float* __restrict__ list_w,
                   const ushort_t* __restrict__ wt1f,
                   const ushort_t* __restrict__ wt2f,
                   const ushort_t* __restrict__ wotf,
                   const float* __restrict__ b1,
                   const float* __restrict__ b2,
                   float* __restrict__ out) {
    int e = blockIdx.x & 7;
    int t0 = blockIdx.x >> 3;
    int cnt = counts[e * 32];

    __shared__ __align__(16) ushort_t bufH[16384]; // 32KB: x chunks, h1, h2
    __shared__ int toks_s[MT];
    __shared__ float wts_s[MT];

    int tid = threadIdx.x;
    int lane = tid & 63;
    int w = tid >> 6;
    int q = lane >> 4;
    int mcol = lane & 15;

    const bf16x8* W1A = (const bf16x8*)(wt1f + (size_t)e * 4096 * 8);
    const bf16x8* W2A = (const bf16x8*)(wt2f + (size_t)e * 8192 * 8);
    const bf16x8* WoB = (const bf16x8*)wotf;
    const bf16x8* Hlbs = (const bf16x8*)bufH;

    // loop-invariant biases: lane (q) needs h-idx n0 = w*64 + rtl*16 + q*4 .. +3
    float4 b1v[4], b2v[4];
#pragma unroll
    for (int rtl = 0; rtl < 4; rtl++) {
        b1v[rtl] = *(const float4*)(b1 + e * HD + w * 64 + rtl * 16 + q * 4);
        b2v[rtl] = *(const float4*)(b2 + e * HD + w * 64 + rtl * 16 + q * 4);
    }

    for (int tile = t0; tile * MT < cnt; tile += NB_T) {
        int base = tile * MT;
        int rows = cnt - base; if (rows > MT) rows = MT;

        __syncthreads(); // prev iteration's GEMM3/combine done before restage

        if (tid < MT) {
            int rr = tid < rows ? tid : rows - 1;
            toks_s[tid] = list_tok[(size_t)e * N_TOK + base + rr];
            wts_s[tid] = list_w[(size_t)e * N_TOK + base + rr];
        }

        // prefetch GEMM1 A-frags (kstep 0) while staging runs
        bf16x8 a1r[2][4];
#pragma unroll
        for (int rtl = 0; rtl < 4; rtl++)
            a1r[0][rtl] = W1A[((w * 4 + rtl) * 4 + 0) * 64 + lane];

        // stage x tile (fp32 -> bf16) into chunk layout (chunks 0..1023)
        for (int c = tid; c < 1024; c += 256) {
            int row = c >> 4;
            int kchunk = c & 15;
            int rr = row < rows ? row : rows - 1;
            int tok = list_tok[(size_t)e * N_TOK + base + rr];
            const float4* src = (const float4*)(x + (size_t)tok * DIN + kchunk * 8);
            float4 lo = src[0], hi = src[1];
            unsigned p0, p1, p2, p3;
            asm("v_cvt_pk_bf16_f32 %0, %1, %2" : "=v"(p0) : "v"(lo.x), "v"(lo.y));
            asm("v_cvt_pk_bf16_f32 %0, %1, %2" : "=v"(p1) : "v"(lo.z), "v"(lo.w));
            asm("v_cvt_pk_bf16_f32 %0, %1, %2" : "=v"(p2) : "v"(hi.x), "v"(hi.y));
            asm("v_cvt_pk_bf16_f32 %0, %1, %2" : "=v"(p3) : "v"(hi.z), "v"(hi.w));
            int dchunk = ((kchunk >> 2) * 4 + (row >> 4)) * 64 + (kchunk & 3) * 16 + (row & 15);
            u32x4 v; v.x = p0; v.y = p1; v.z = p2; v.w = p3;
            *(u32x4*)(&bufH[dchunk * 8]) = v;
        }
        __syncthreads();

        // ---- GEMM1 (swapped): h1^T[n=256][t=64], wave w owns n rows w*64..+63
        f32x4 acc[4][4]; // [rtl][ct]
#pragma unroll
        for (int rtl = 0; rtl < 4; rtl++)
#pragma unroll
            for (int ct = 0; ct < 4; ct++) acc[rtl][ct] = (f32x4){0.f, 0.f, 0.f, 0.f};
#pragma unroll
        for (int ks = 0; ks < 4; ks++) {
            const int cur = ks & 1, nxt = cur ^ 1;
            if (ks < 3) {
#pragma unroll
                for (int rtl = 0; rtl < 4; rtl++)
                    a1r[nxt][rtl] = W1A[((w * 4 + rtl) * 4 + ks + 1) * 64 + lane];
            }
            bf16x8 bf_[4];
#pragma unroll
            for (int ct = 0; ct < 4; ct++) bf_[ct] = Hlbs[(ks * 4 + ct) * 64 + lane];
#pragma unroll
            for (int rtl = 0; rtl < 4; rtl++)
#pragma unroll
                for (int ct = 0; ct < 4; ct++)
                    acc[rtl][ct] = __builtin_amdgcn_mfma_f32_16x16x32_bf16(a1r[cur][rtl], bf_[ct], acc[rtl][ct], 0, 0, 0);
        }
        // prefetch GEMM2 A-frags (kstep 0); in flight across epilogue 1
        bf16x8 a2r[2][4];
#pragma unroll
        for (int rtl = 0; rtl < 4; rtl++)
            a2r[0][rtl] = W2A[((w * 4 + rtl) * 8 + 0) * 64 + lane];

        __syncthreads(); // all waves done reading x chunks before h1 overwrite

        // epilogue 1: bias + relu -> h1 chunks (contiguous b64 stores)
#pragma unroll
        for (int rtl = 0; rtl < 4; rtl++) {
            int ks2 = w * 2 + (rtl >> 1);
            int q2 = (rtl * 2 + (q >> 1)) & 3;
            int uoff = (ks2 * 4 * 64 + q2 * 16 + mcol) * 8 + (q & 1) * 4;
#pragma unroll
            for (int ct = 0; ct < 4; ct++) {
                float v0 = acc[rtl][ct][0] + b1v[rtl].x; v0 = v0 > 0.f ? v0 : 0.f;
                float v1 = acc[rtl][ct][1] + b1v[rtl].y; v1 = v1 > 0.f ? v1 : 0.f;
                float v2 = acc[rtl][ct][2] + b1v[rtl].z; v2 = v2 > 0.f ? v2 : 0.f;
                float v3 = acc[rtl][ct][3] + b1v[rtl].w; v3 = v3 > 0.f ? v3 : 0.f;
                unsigned d0, d1;
                asm("v_cvt_pk_bf16_f32 %0, %1, %2" : "=v"(d0) : "v"(v0), "v"(v1));
                asm("v_cvt_pk_bf16_f32 %0, %1, %2" : "=v"(d1) : "v"(v2), "v"(v3));
                u32x2 dd; dd.x = d0; dd.y = d1;
                *(u32x2*)(&bufH[uoff + ct * 512]) = dd;
            }
        }
        __syncthreads();

        // ---- GEMM2 (swapped): h2^T = W2^T @ h1^T, K=256 ----
        f32x4 acc2[4][4];
#pragma unroll
        for (int rtl = 0; rtl < 4; rtl++)
#pragma unroll
            for (int ct = 0; ct < 4; ct++) acc2[rtl][ct] = (f32x4){0.f, 0.f, 0.f, 0.f};
#pragma unroll
        for (int ks = 0; ks < 8; ks++) {
            const int cur = ks & 1, nxt = cur ^ 1;
            if (ks < 7) {
#pragma unroll
                for (int rtl = 0; rtl < 4; rtl++)
                    a2r[nxt][rtl] = W2A[((w * 4 + rtl) * 8 + ks + 1) * 64 + lane];
            }
            bf16x8 bf_[4];
#pragma unroll
            for (int ct = 0; ct < 4; ct++) bf_[ct] = Hlbs[(ks * 4 + ct) * 64 + lane];
#pragma unroll
            for (int rtl = 0; rtl < 4; rtl++)
#pragma unroll
                for (int ct = 0; ct < 4; ct++)
                    acc2[rtl][ct] = __builtin_amdgcn_mfma_f32_16x16x32_bf16(a2r[cur][rtl], bf_[ct], acc2[rtl][ct], 0, 0, 0);
        }
        // prefetch GEMM3 B-frags (kstep 0); in flight across epilogue 2
        bf16x8 b3r[2][2];
#pragma unroll
        for (int nt = 0; nt < 2; nt++)
            b3r[0][nt] = WoB[((w * 2 + nt) * 8 + 0) * 64 + lane];

        __syncthreads(); // all waves done reading h1 before h2 overwrite

        // epilogue 2: bias + relu -> h2 chunks
#pragma unroll
        for (int rtl = 0; rtl < 4; rtl++) {
            int ks2 = w * 2 + (rtl >> 1);
            int q2 = (rtl * 2 + (q >> 1)) & 3;
            int uoff = (ks2 * 4 * 64 + q2 * 16 + mcol) * 8 + (q & 1) * 4;
#pragma unroll
            for (int ct = 0; ct < 4; ct++) {
                float v0 = acc2[rtl][ct][0] + b2v[rtl].x; v0 = v0 > 0.f ? v0 : 0.f;
                float v1 = acc2[rtl][ct][1] + b2v[rtl].y; v1 = v1 > 0.f ? v1 : 0.f;
                float v2 = acc2[rtl][ct][2] + b2v[rtl].z; v2 = v2 > 0.f ? v2 : 0.f;
                float v3 = acc2[rtl][ct][3] + b2v[rtl].w; v3 = v3 > 0.f ? v3 : 0.f;
                unsigned d0, d1;
                asm("v_cvt_pk_bf16_f32 %0, %1, %2" : "=v"(d0) : "v"(v0), "v"(v1));
                asm("v_cvt_pk_bf16_f32 %0, %1, %2" : "=v"(d1) : "v"(v2), "v"(v3));
                u32x2 dd; dd.x = d0; dd.y = d1;
                *(u32x2*)(&bufH[uoff + ct * 512]) = dd;
            }
        }
        __syncthreads();

        // ---- GEMM3 (unswapped): y = h2 @ Wo; weighted atomic combine ----
        f32x4 acc3[4][2]; // [mt][nt]
#pragma unroll
        for (int mt = 0; mt < 4; mt++)
#pragma unroll
            for (int nt = 0; nt < 2; nt++) acc3[mt][nt] = (f32x4){0.f, 0.f, 0.f, 0.f};
#pragma unroll
        for (int ks = 0; ks < 8; ks++) {
            const int cur = ks & 1, nxt = cur ^ 1;
            if (ks < 7) {
#pragma unroll
                for (int nt = 0; nt < 2; nt++)
                    b3r[nxt][nt] = WoB[((w * 2 + nt) * 8 + ks + 1) * 64 + lane];
            }
            bf16x8 af_[4];
#pragma unroll
            for (int mt = 0; mt < 4; mt++) af_[mt] = Hlbs[(ks * 4 + mt) * 64 + lane];
#pragma unroll
            for (int nt = 0; nt < 2; nt++)
#pragma unroll
                for (int mt = 0; mt < 4; mt++)
                    acc3[mt][nt] = __builtin_amdgcn_mfma_f32_16x16x32_bf16(af_[mt], b3r[cur][nt], acc3[mt][nt], 0, 0, 0);
        }
#pragma unroll
        for (int mt = 0; mt < 4; mt++) {
#pragma unroll
            for (int r = 0; r < 4; r++) {
                int row = mt * 16 + q * 4 + r;
                if (row < rows) {
                    int tok = toks_s[row];
                    float wgt = wts_s[row];
                    float* dst = out + (size_t)tok * DOUT;
#pragma unroll
                    for (int nt = 0; nt < 2; nt++) {
                        int col = (w * 2 + nt) * 16 + mcol;
                        atomicAdd(&dst[col], wgt * acc3[mt][nt][r]);
                    }
                }
            }
        }
    }
}

extern "C" void kernel_launch(void* const* d_in, const int* in_sizes, int n_in,
                              void* d_out, int out_size, void* d_ws, size_t ws_size,
                              hipStream_t stream) {
    const float* x  = (const float*)d_in[0];
    const float* Wg = (const float*)d_in[1];
    const float* W1 = (const float*)d_in[2];
    const float* b1 = (const float*)d_in[3];
    const float* W2 = (const float*)d_in[4];
    const float* b2 = (const float*)d_in[5];
    const float* Wo = (const float*)d_in[6];
    const float* bo = (const float*)d_in[7];
    float* out = (float*)d_out;

    char* ws = (char*)d_ws;
    size_t off = 0;
    int* counts    = (int*)(ws + off);    off += 1024;  // 8 counters, 128B apart
    int* list_tok  = (int*)(ws + off);    off += (size_t)NEXP * N_TOK * 4;
    float* list_w  = (float*)(ws + off);  off += (size_t)NEXP * N_TOK * 4;
    ushort_t* wt1f = (ushort_t*)(ws + off); off += (size_t)NEXP * DIN * HD * 2;
    ushort_t* wt2f = (ushort_t*)(ws + off); off += (size_t)NEXP * HD * HD * 2;
    ushort_t* wotf = (ushort_t*)(ws + off); off += (size_t)HD * DOUT * 2;

    hipMemsetAsync(counts, 0, 1024, stream);
    router_kernel<<<N_TOK / RT_TPB, RT_BLOCK, 0, stream>>>(
        x, Wg, W1, W2, Wo, bo, counts, list_tok, list_w, wt1f, wt2f, wotf, out);
    expert_kernel<<<NEXP * NB_T, 256, 0, stream>>>(x, counts, list_tok, list_w,
                                                   wt1f, wt2f, wotf, b1, b2, out);
}

// Round 3
// 267.369 us; speedup vs baseline: 1.2011x; 1.2011x over previous
//
#include <hip/hip_runtime.h>
#include <math.h>

typedef unsigned short ushort_t;
typedef __attribute__((ext_vector_type(8))) short bf16x8;
typedef __attribute__((ext_vector_type(4))) float f32x4;
typedef __attribute__((ext_vector_type(8))) unsigned short u16x8;
typedef __attribute__((ext_vector_type(2))) unsigned int u32x2;
typedef __attribute__((ext_vector_type(4))) unsigned int u32x4;

#define N_TOK 65536
#define DIN 128
#define HD 256
#define DOUT 128
#define NEXP 8
#define MT 64
#define NB_T 320   /* tile-blocks per expert; grid-stride covers overflow */

__device__ __forceinline__ unsigned short f2bf(float f) {
    union { float f; unsigned int i; } v; v.f = f;
    unsigned int i = v.i;
    return (unsigned short)((i + 0x7FFFu + ((i >> 16) & 1u)) >> 16); // RNE
}

#define RT_BLOCK 1024
#define RT_TPB 128   /* tokens per block */

// ---------------------------------------------------------------------------
// Fused router + weight-pack + out-init (structure unchanged from round 2;
// logit loop unroll capped at 8 to bound live-load register pressure).
// ---------------------------------------------------------------------------
__global__ __launch_bounds__(RT_BLOCK)
void router_kernel(const float* __restrict__ x,
                   const float* __restrict__ Wg,
                   const float* __restrict__ W1,
                   const float* __restrict__ W2,
                   const float* __restrict__ Wo,
                   const float* __restrict__ bo,
                   int* __restrict__ counts,
                   int* __restrict__ list_tok,
                   float* __restrict__ list_w,
                   ushort_t* __restrict__ wt1f,
                   ushort_t* __restrict__ wt2f,
                   ushort_t* __restrict__ wotf,
                   float* __restrict__ out) {
    __shared__ float wgsT[NEXP * 132]; // padded leading dim: conflict-free b128
    __shared__ int lcnt[NEXP];
    __shared__ int lbase[NEXP];
    int tid = threadIdx.x;
    if (tid < NEXP) lcnt[tid] = 0;
    if (tid < DIN * NEXP) {
        int ee = tid & 7, k = tid >> 3;   // Wg[k][e]
        wgsT[ee * 132 + k] = Wg[tid];
    }
    // fused init_out: this block's 128 tokens
    {
        const float4* bo4 = (const float4*)bo;
        float4* ob = (float4*)(out + (size_t)blockIdx.x * RT_TPB * DOUT);
#pragma unroll
        for (int i = 0; i < 4; i++) {
            int idx = i * RT_BLOCK + tid;       // 0..4095
            ob[idx] = bo4[idx & 31];
        }
    }
    // fused pack_weights: 100 blocks x 1024 threads = 102400 chunks
    if (blockIdx.x < 100) {
        int id = blockIdx.x * RT_BLOCK + tid;
        const float* src; ushort_t* dst; int Nn, ksteps, c;
        if (id < 32768) {            // W1
            int ee = id >> 12; c = id & 4095;
            Nn = HD; ksteps = 4; src = W1 + (size_t)ee * DIN * HD; dst = wt1f + (size_t)id * 8;
        } else if (id < 98304) {     // W2
            int t = id - 32768; int ee = t >> 13; c = t & 8191;
            Nn = HD; ksteps = 8; src = W2 + (size_t)ee * HD * HD; dst = wt2f + (size_t)t * 8;
        } else {                     // Wo
            int t = id - 98304; c = t;
            Nn = DOUT; ksteps = 8; src = Wo; dst = wotf + (size_t)t * 8;
        }
        int L = c & 63; int kc = c >> 6;
        int kstep = kc % ksteps; int ntile = kc / ksteps;
        int qq = L >> 4, mm = L & 15;
        int n = ntile * 16 + mm; int k0 = kstep * 32 + qq * 8;
        u16x8 v;
#pragma unroll
        for (int j = 0; j < 8; j++) v[j] = f2bf(src[(size_t)(k0 + j) * Nn + n]);
        *(u16x8*)dst = v;
    }
    __syncthreads();

    int e = tid & 7;
    int tl = tid >> 3;
    int n = blockIdx.x * RT_TPB + tl;
    const float4* xr = (const float4*)(x + (size_t)n * DIN);
    const float4* wv4 = (const float4*)(wgsT + e * 132);
    float lg = 0.f;
#pragma unroll 8
    for (int kk = 0; kk < 32; kk++) {
        float4 xv = xr[kk];
        float4 wv = wv4[kk];
        lg += xv.x * wv.x;
        lg += xv.y * wv.y;
        lg += xv.z * wv.z;
        lg += xv.w * wv.w;
    }
    // top-1 over the 8 lanes of this token (ties -> lowest expert index)
    float v0 = lg; int e0 = e;
#pragma unroll
    for (int d = 1; d < 8; d <<= 1) {
        float ov = __shfl_xor(v0, d, 64);
        int oe = __shfl_xor(e0, d, 64);
        if (ov > v0 || (ov == v0 && oe < e0)) { v0 = ov; e0 = oe; }
    }
    // top-2: mask out e0, reduce again
    float mv = (e == e0) ? -3.0e38f : lg;
    float v1 = mv; int e1 = e;
#pragma unroll
    for (int d = 1; d < 8; d <<= 1) {
        float ov = __shfl_xor(v1, d, 64);
        int oe = __shfl_xor(e1, d, 64);
        if (ov > v1 || (ov == v1 && oe < e1)) { v1 = ov; e1 = oe; }
    }
    float t = expf(v1 - v0);
    float inv = 1.0f / (1.0f + t);
    float w0 = inv, w1 = t * inv;

    bool writer = (e == 0);
    int p0 = 0, p1 = 0;
    if (writer) {
        p0 = atomicAdd(&lcnt[e0], 1);
        p1 = atomicAdd(&lcnt[e1], 1);
    }
    __syncthreads();
    if (tid < NEXP) lbase[tid] = atomicAdd(&counts[tid * 32], lcnt[tid]);
    __syncthreads();
    if (writer) {
        int q0 = lbase[e0] + p0;
        list_tok[e0 * N_TOK + q0] = n;
        list_w[e0 * N_TOK + q0] = w0;
        int q1 = lbase[e1] + p1;
        list_tok[e1 * N_TOK + q1] = n;
        list_w[e1 * N_TOK + q1] = w1;
    }
}

// ---------------------------------------------------------------------------
// Fused per-expert MLP over 64-token tiles, SWAPPED-GEMM form:
//   GEMM1: h1^T = W1^T @ x^T   (A = wt1f pack, B = x chunks in LDS)
//   GEMM2: h2^T = W2^T @ h1^T  (A = wt2f pack, B = h1 chunks in LDS)
//   GEMM3: y    = h2  @ Wo     (A = h2 chunks in LDS, B = wotf pack)
// Single LDS chunk layout serves all three; swapped C-frags hold 4
// consecutive h-indices at a fixed token -> epilogues are cvt_pk pairs +
// one contiguous ds_write_b64 (2-way bank aliasing = free). All LDS reads
// wave-contiguous ds_read_b128. Weight loads pipelined 1 kstep.
//
// __launch_bounds__(256, 3): 170 VGPRs. (256,4) capped at 128 and SPILLED
// (round 2: WRITE_SIZE 67->390MB, dur 75->227us). Occupancy is VGPR-bound
// at 3 blocks/CU; LDS (33.3KB) would allow 4.
// ---------------------------------------------------------------------------
__global__ __launch_bounds__(256, 3)
void expert_kernel(const float* __restrict__ x,
                   const int* __restrict__ counts,
                   const int* __restrict__ list_tok,
                   const float* __restrict__ list_w,
                   const ushort_t* __restrict__ wt1f,
                   const ushort_t* __restrict__ wt2f,
                   const ushort_t* __restrict__ wotf,
                   const float* __restrict__ b1,
                   const float* __restrict__ b2,
                   float* __restrict__ out) {
    int e = blockIdx.x & 7;
    int t0 = blockIdx.x >> 3;
    int cnt = counts[e * 32];

    __shared__ __align__(16) ushort_t bufH[16384]; // 32KB: x chunks, h1, h2
    __shared__ int toks_s[MT];
    __shared__ float wts_s[MT];

    int tid = threadIdx.x;
    int lane = tid & 63;
    int w = tid >> 6;
    int q = lane >> 4;
    int mcol = lane & 15;

    const bf16x8* W1A = (const bf16x8*)(wt1f + (size_t)e * 4096 * 8);
    const bf16x8* W2A = (const bf16x8*)(wt2f + (size_t)e * 8192 * 8);
    const bf16x8* WoB = (const bf16x8*)wotf;
    const bf16x8* Hlbs = (const bf16x8*)bufH;

    // loop-invariant biases: lane (q) needs h-idx n0 = w*64 + rtl*16 + q*4 .. +3
    float4 b1v[4], b2v[4];
#pragma unroll
    for (int rtl = 0; rtl < 4; rtl++) {
        b1v[rtl] = *(const float4*)(b1 + e * HD + w * 64 + rtl * 16 + q * 4);
        b2v[rtl] = *(const float4*)(b2 + e * HD + w * 64 + rtl * 16 + q * 4);
    }

    for (int tile = t0; tile * MT < cnt; tile += NB_T) {
        int base = tile * MT;
        int rows = cnt - base; if (rows > MT) rows = MT;

        __syncthreads(); // prev iteration's GEMM3/combine done before restage

        if (tid < MT) {
            int rr = tid < rows ? tid : rows - 1;
            toks_s[tid] = list_tok[(size_t)e * N_TOK + base + rr];
            wts_s[tid] = list_w[(size_t)e * N_TOK + base + rr];
        }

        // prefetch GEMM1 A-frags (kstep 0) while staging runs
        bf16x8 a1r[2][4];
#pragma unroll
        for (int rtl = 0; rtl < 4; rtl++)
            a1r[0][rtl] = W1A[((w * 4 + rtl) * 4 + 0) * 64 + lane];

        // stage x tile (fp32 -> bf16) into chunk layout (chunks 0..1023)
        for (int c = tid; c < 1024; c += 256) {
            int row = c >> 4;
            int kchunk = c & 15;
            int rr = row < rows ? row : rows - 1;
            int tok = list_tok[(size_t)e * N_TOK + base + rr];
            const float4* src = (const float4*)(x + (size_t)tok * DIN + kchunk * 8);
            float4 lo = src[0], hi = src[1];
            unsigned p0, p1, p2, p3;
            asm("v_cvt_pk_bf16_f32 %0, %1, %2" : "=v"(p0) : "v"(lo.x), "v"(lo.y));
            asm("v_cvt_pk_bf16_f32 %0, %1, %2" : "=v"(p1) : "v"(lo.z), "v"(lo.w));
            asm("v_cvt_pk_bf16_f32 %0, %1, %2" : "=v"(p2) : "v"(hi.x), "v"(hi.y));
            asm("v_cvt_pk_bf16_f32 %0, %1, %2" : "=v"(p3) : "v"(hi.z), "v"(hi.w));
            int dchunk = ((kchunk >> 2) * 4 + (row >> 4)) * 64 + (kchunk & 3) * 16 + (row & 15);
            u32x4 v; v.x = p0; v.y = p1; v.z = p2; v.w = p3;
            *(u32x4*)(&bufH[dchunk * 8]) = v;
        }
        __syncthreads();

        // ---- GEMM1 (swapped): h1^T[n=256][t=64], wave w owns n rows w*64..+63
        f32x4 acc[4][4]; // [rtl][ct]
#pragma unroll
        for (int rtl = 0; rtl < 4; rtl++)
#pragma unroll
            for (int ct = 0; ct < 4; ct++) acc[rtl][ct] = (f32x4){0.f, 0.f, 0.f, 0.f};
#pragma unroll
        for (int ks = 0; ks < 4; ks++) {
            const int cur = ks & 1, nxt = cur ^ 1;
            if (ks < 3) {
#pragma unroll
                for (int rtl = 0; rtl < 4; rtl++)
                    a1r[nxt][rtl] = W1A[((w * 4 + rtl) * 4 + ks + 1) * 64 + lane];
            }
            bf16x8 bf_[4];
#pragma unroll
            for (int ct = 0; ct < 4; ct++) bf_[ct] = Hlbs[(ks * 4 + ct) * 64 + lane];
#pragma unroll
            for (int rtl = 0; rtl < 4; rtl++)
#pragma unroll
                for (int ct = 0; ct < 4; ct++)
                    acc[rtl][ct] = __builtin_amdgcn_mfma_f32_16x16x32_bf16(a1r[cur][rtl], bf_[ct], acc[rtl][ct], 0, 0, 0);
        }
        // prefetch GEMM2 A-frags (kstep 0); in flight across epilogue 1
        bf16x8 a2r[2][4];
#pragma unroll
        for (int rtl = 0; rtl < 4; rtl++)
            a2r[0][rtl] = W2A[((w * 4 + rtl) * 8 + 0) * 64 + lane];

        __syncthreads(); // all waves done reading x chunks before h1 overwrite

        // epilogue 1: bias + relu -> h1 chunks (contiguous b64 stores)
#pragma unroll
        for (int rtl = 0; rtl < 4; rtl++) {
            int ks2 = w * 2 + (rtl >> 1);
            int q2 = (rtl * 2 + (q >> 1)) & 3;
            int uoff = (ks2 * 4 * 64 + q2 * 16 + mcol) * 8 + (q & 1) * 4;
#pragma unroll
            for (int ct = 0; ct < 4; ct++) {
                float v0 = acc[rtl][ct][0] + b1v[rtl].x; v0 = v0 > 0.f ? v0 : 0.f;
                float v1 = acc[rtl][ct][1] + b1v[rtl].y; v1 = v1 > 0.f ? v1 : 0.f;
                float v2 = acc[rtl][ct][2] + b1v[rtl].z; v2 = v2 > 0.f ? v2 : 0.f;
                float v3 = acc[rtl][ct][3] + b1v[rtl].w; v3 = v3 > 0.f ? v3 : 0.f;
                unsigned d0, d1;
                asm("v_cvt_pk_bf16_f32 %0, %1, %2" : "=v"(d0) : "v"(v0), "v"(v1));
                asm("v_cvt_pk_bf16_f32 %0, %1, %2" : "=v"(d1) : "v"(v2), "v"(v3));
                u32x2 dd; dd.x = d0; dd.y = d1;
                *(u32x2*)(&bufH[uoff + ct * 512]) = dd;
            }
        }
        __syncthreads();

        // ---- GEMM2 (swapped): h2^T = W2^T @ h1^T, K=256 ----
        f32x4 acc2[4][4];
#pragma unroll
        for (int rtl = 0; rtl < 4; rtl++)
#pragma unroll
            for (int ct = 0; ct < 4; ct++) acc2[rtl][ct] = (f32x4){0.f, 0.f, 0.f, 0.f};
#pragma unroll
        for (int ks = 0; ks < 8; ks++) {
            const int cur = ks & 1, nxt = cur ^ 1;
            if (ks < 7) {
#pragma unroll
                for (int rtl = 0; rtl < 4; rtl++)
                    a2r[nxt][rtl] = W2A[((w * 4 + rtl) * 8 + ks + 1) * 64 + lane];
            }
            bf16x8 bf_[4];
#pragma unroll
            for (int ct = 0; ct < 4; ct++) bf_[ct] = Hlbs[(ks * 4 + ct) * 64 + lane];
#pragma unroll
            for (int rtl = 0; rtl < 4; rtl++)
#pragma unroll
                for (int ct = 0; ct < 4; ct++)
                    acc2[rtl][ct] = __builtin_amdgcn_mfma_f32_16x16x32_bf16(a2r[cur][rtl], bf_[ct], acc2[rtl][ct], 0, 0, 0);
        }
        // prefetch GEMM3 B-frags (kstep 0); in flight across epilogue 2
        bf16x8 b3r[2][2];
#pragma unroll
        for (int nt = 0; nt < 2; nt++)
            b3r[0][nt] = WoB[((w * 2 + nt) * 8 + 0) * 64 + lane];

        __syncthreads(); // all waves done reading h1 before h2 overwrite

        // epilogue 2: bias + relu -> h2 chunks
#pragma unroll
        for (int rtl = 0; rtl < 4; rtl++) {
            int ks2 = w * 2 + (rtl >> 1);
            int q2 = (rtl * 2 + (q >> 1)) & 3;
            int uoff = (ks2 * 4 * 64 + q2 * 16 + mcol) * 8 + (q & 1) * 4;
#pragma unroll
            for (int ct = 0; ct < 4; ct++) {
                float v0 = acc2[rtl][ct][0] + b2v[rtl].x; v0 = v0 > 0.f ? v0 : 0.f;
                float v1 = acc2[rtl][ct][1] + b2v[rtl].y; v1 = v1 > 0.f ? v1 : 0.f;
                float v2 = acc2[rtl][ct][2] + b2v[rtl].z; v2 = v2 > 0.f ? v2 : 0.f;
                float v3 = acc2[rtl][ct][3] + b2v[rtl].w; v3 = v3 > 0.f ? v3 : 0.f;
                unsigned d0, d1;
                asm("v_cvt_pk_bf16_f32 %0, %1, %2" : "=v"(d0) : "v"(v0), "v"(v1));
                asm("v_cvt_pk_bf16_f32 %0, %1, %2" : "=v"(d1) : "v"(v2), "v"(v3));
                u32x2 dd; dd.x = d0; dd.y = d1;
                *(u32x2*)(&bufH[uoff + ct * 512]) = dd;
            }
        }
        __syncthreads();

        // ---- GEMM3 (unswapped): y = h2 @ Wo; weighted atomic combine ----
        f32x4 acc3[4][2]; // [mt][nt]
#pragma unroll
        for (int mt = 0; mt < 4; mt++)
#pragma unroll
            for (int nt = 0; nt < 2; nt++) acc3[mt][nt] = (f32x4){0.f, 0.f, 0.f, 0.f};
#pragma unroll
        for (int ks = 0; ks < 8; ks++) {
            const int cur = ks & 1, nxt = cur ^ 1;
            if (ks < 7) {
#pragma unroll
                for (int nt = 0; nt < 2; nt++)
                    b3r[nxt][nt] = WoB[((w * 2 + nt) * 8 + ks + 1) * 64 + lane];
            }
            bf16x8 af_[4];
#pragma unroll
            for (int mt = 0; mt < 4; mt++) af_[mt] = Hlbs[(ks * 4 + mt) * 64 + lane];
#pragma unroll
            for (int nt = 0; nt < 2; nt++)
#pragma unroll
                for (int mt = 0; mt < 4; mt++)
                    acc3[mt][nt] = __builtin_amdgcn_mfma_f32_16x16x32_bf16(af_[mt], b3r[cur][nt], acc3[mt][nt], 0, 0, 0);
        }
#pragma unroll
        for (int mt = 0; mt < 4; mt++) {
#pragma unroll
            for (int r = 0; r < 4; r++) {
                int row = mt * 16 + q * 4 + r;
                if (row < rows) {
                    int tok = toks_s[row];
                    float wgt = wts_s[row];
                    float* dst = out + (size_t)tok * DOUT;
#pragma unroll
                    for (int nt = 0; nt < 2; nt++) {
                        int col = (w * 2 + nt) * 16 + mcol;
                        atomicAdd(&dst[col], wgt * acc3[mt][nt][r]);
                    }
                }
            }
        }
    }
}

extern "C" void kernel_launch(void* const* d_in, const int* in_sizes, int n_in,
                              void* d_out, int out_size, void* d_ws, size_t ws_size,
                              hipStream_t stream) {
    const float* x  = (const float*)d_in[0];
    const float* Wg = (const float*)d_in[1];
    const float* W1 = (const float*)d_in[2];
    const float* b1 = (const float*)d_in[3];
    const float* W2 = (const float*)d_in[4];
    const float* b2 = (const float*)d_in[5];
    const float* Wo = (const float*)d_in[6];
    const float* bo = (const float*)d_in[7];
    float* out = (float*)d_out;

    char* ws = (char*)d_ws;
    size_t off = 0;
    int* counts    = (int*)(ws + off);    off += 1024;  // 8 counters, 128B apart
    int* list_tok  = (int*)(ws + off);    off += (size_t)NEXP * N_TOK * 4;
    float* list_w  = (float*)(ws + off);  off += (size_t)NEXP * N_TOK * 4;
    ushort_t* wt1f = (ushort_t*)(ws + off); off += (size_t)NEXP * DIN * HD * 2;
    ushort_t* wt2f = (ushort_t*)(ws + off); off += (size_t)NEXP * HD * HD * 2;
    ushort_t* wotf = (ushort_t*)(ws + off); off += (size_t)HD * DOUT * 2;

    hipMemsetAsync(counts, 0, 1024, stream);
    router_kernel<<<N_TOK / RT_TPB, RT_BLOCK, 0, stream>>>(
        x, Wg, W1, W2, Wo, bo, counts, list_tok, list_w, wt1f, wt2f, wotf, out);
    expert_kernel<<<NEXP * NB_T, 256, 0, stream>>>(x, counts, list_tok, list_w,
                                                   wt1f, wt2f, wotf, b1, b2, out);
}

// Round 4
// 197.832 us; speedup vs baseline: 1.6233x; 1.3515x over previous
//
#include <hip/hip_runtime.h>
#include <math.h>

typedef unsigned short ushort_t;
typedef __attribute__((ext_vector_type(8))) short bf16x8;
typedef __attribute__((ext_vector_type(4))) float f32x4;
typedef __attribute__((ext_vector_type(8))) unsigned short u16x8;
typedef __attribute__((ext_vector_type(2))) unsigned int u32x2;
typedef __attribute__((ext_vector_type(4))) unsigned int u32x4;

#define N_TOK 65536
#define DIN 128
#define HD 256
#define DOUT 128
#define NEXP 8
#define MT 64
#define MAX_TILES (N_TOK / MT) /* 1024 */

__device__ __forceinline__ unsigned short f2bf(float f) {
    union { float f; unsigned int i; } v; v.f = f;
    unsigned int i = v.i;
    return (unsigned short)((i + 0x7FFFu + ((i >> 16) & 1u)) >> 16); // RNE
}

#define RT_BLOCK 1024
#define RT_TPB 128   /* tokens per block */

// ---------------------------------------------------------------------------
// Fused router + weight-pack + out-init (unchanged from round 3).
// ---------------------------------------------------------------------------
__global__ __launch_bounds__(RT_BLOCK)
void router_kernel(const float* __restrict__ x,
                   const float* __restrict__ Wg,
                   const float* __restrict__ W1,
                   const float* __restrict__ W2,
                   const float* __restrict__ Wo,
                   const float* __restrict__ bo,
                   int* __restrict__ counts,
                   int* __restrict__ list_tok,
                   float* __restrict__ list_w,
                   ushort_t* __restrict__ wt1f,
                   ushort_t* __restrict__ wt2f,
                   ushort_t* __restrict__ wotf,
                   float* __restrict__ out) {
    __shared__ float wgsT[NEXP * 132]; // padded leading dim: conflict-free b128
    __shared__ int lcnt[NEXP];
    __shared__ int lbase[NEXP];
    int tid = threadIdx.x;
    if (tid < NEXP) lcnt[tid] = 0;
    if (tid < DIN * NEXP) {
        int ee = tid & 7, k = tid >> 3;   // Wg[k][e]
        wgsT[ee * 132 + k] = Wg[tid];
    }
    // fused init_out: this block's 128 tokens
    {
        const float4* bo4 = (const float4*)bo;
        float4* ob = (float4*)(out + (size_t)blockIdx.x * RT_TPB * DOUT);
#pragma unroll
        for (int i = 0; i < 4; i++) {
            int idx = i * RT_BLOCK + tid;       // 0..4095
            ob[idx] = bo4[idx & 31];
        }
    }
    // fused pack_weights: 100 blocks x 1024 threads = 102400 chunks
    if (blockIdx.x < 100) {
        int id = blockIdx.x * RT_BLOCK + tid;
        const float* src; ushort_t* dst; int Nn, ksteps, c;
        if (id < 32768) {            // W1
            int ee = id >> 12; c = id & 4095;
            Nn = HD; ksteps = 4; src = W1 + (size_t)ee * DIN * HD; dst = wt1f + (size_t)id * 8;
        } else if (id < 98304) {     // W2
            int t = id - 32768; int ee = t >> 13; c = t & 8191;
            Nn = HD; ksteps = 8; src = W2 + (size_t)ee * HD * HD; dst = wt2f + (size_t)t * 8;
        } else {                     // Wo
            int t = id - 98304; c = t;
            Nn = DOUT; ksteps = 8; src = Wo; dst = wotf + (size_t)t * 8;
        }
        int L = c & 63; int kc = c >> 6;
        int kstep = kc % ksteps; int ntile = kc / ksteps;
        int qq = L >> 4, mm = L & 15;
        int n = ntile * 16 + mm; int k0 = kstep * 32 + qq * 8;
        u16x8 v;
#pragma unroll
        for (int j = 0; j < 8; j++) v[j] = f2bf(src[(size_t)(k0 + j) * Nn + n]);
        *(u16x8*)dst = v;
    }
    __syncthreads();

    int e = tid & 7;
    int tl = tid >> 3;
    int n = blockIdx.x * RT_TPB + tl;
    const float4* xr = (const float4*)(x + (size_t)n * DIN);
    const float4* wv4 = (const float4*)(wgsT + e * 132);
    float lg = 0.f;
#pragma unroll 8
    for (int kk = 0; kk < 32; kk++) {
        float4 xv = xr[kk];
        float4 wv = wv4[kk];
        lg += xv.x * wv.x;
        lg += xv.y * wv.y;
        lg += xv.z * wv.z;
        lg += xv.w * wv.w;
    }
    // top-1 over the 8 lanes of this token (ties -> lowest expert index)
    float v0 = lg; int e0 = e;
#pragma unroll
    for (int d = 1; d < 8; d <<= 1) {
        float ov = __shfl_xor(v0, d, 64);
        int oe = __shfl_xor(e0, d, 64);
        if (ov > v0 || (ov == v0 && oe < e0)) { v0 = ov; e0 = oe; }
    }
    // top-2: mask out e0, reduce again
    float mv = (e == e0) ? -3.0e38f : lg;
    float v1 = mv; int e1 = e;
#pragma unroll
    for (int d = 1; d < 8; d <<= 1) {
        float ov = __shfl_xor(v1, d, 64);
        int oe = __shfl_xor(e1, d, 64);
        if (ov > v1 || (ov == v1 && oe < e1)) { v1 = ov; e1 = oe; }
    }
    float t = expf(v1 - v0);
    float inv = 1.0f / (1.0f + t);
    float w0 = inv, w1 = t * inv;

    bool writer = (e == 0);
    int p0 = 0, p1 = 0;
    if (writer) {
        p0 = atomicAdd(&lcnt[e0], 1);
        p1 = atomicAdd(&lcnt[e1], 1);
    }
    __syncthreads();
    if (tid < NEXP) lbase[tid] = atomicAdd(&counts[tid * 32], lcnt[tid]);
    __syncthreads();
    if (writer) {
        int q0 = lbase[e0] + p0;
        list_tok[e0 * N_TOK + q0] = n;
        list_w[e0 * N_TOK + q0] = w0;
        int q1 = lbase[e1] + p1;
        list_tok[e1 * N_TOK + q1] = n;
        list_w[e1 * N_TOK + q1] = w1;
    }
}

// ---------------------------------------------------------------------------
// Fused per-expert MLP, one 64-token tile per block, SWAPPED-GEMM form:
//   GEMM1: h1^T = W1^T @ x^T   (A = wt1f pack, B = x chunks in LDS)
//   GEMM2: h2^T = W2^T @ h1^T  (A = wt2f pack, B = h1 chunks in LDS)
//   GEMM3: y    = h2  @ Wo     (A = h2 chunks in LDS, B = wotf pack)
// Swapped C-frags hold 4 consecutive h-indices at a fixed token -> epilogues
// are cvt_pk pairs + one contiguous ds_write_b64. All GEMM LDS reads are
// wave-contiguous ds_read_b128 (conflict-free). x-staging maps ROW to the
// fast thread index: each wave writes 4 contiguous 256B LDS rows
// (conflict-free; the old kchunk-fast map was a 16-way, 4-bank pattern).
//
// CONTROL-FLOW NOTE (rounds 2/3 post-mortem): a grid-stride tile loop makes
// loop-invariants + accumulators live across the back-edge and the allocator
// spills to scratch (WRITE_SIZE 67->300..390MB, dur 75->161..227us) even at
// (256,3). One-tile-per-block with JIT bias loads compiles spill-free.
// ---------------------------------------------------------------------------
__global__ __launch_bounds__(256, 3)
void expert_kernel(const float* __restrict__ x,
                   const int* __restrict__ counts,
                   const int* __restrict__ list_tok,
                   const float* __restrict__ list_w,
                   const ushort_t* __restrict__ wt1f,
                   const ushort_t* __restrict__ wt2f,
                   const ushort_t* __restrict__ wotf,
                   const float* __restrict__ b1,
                   const float* __restrict__ b2,
                   float* __restrict__ out) {
    int e = blockIdx.x & 7;
    int tile = blockIdx.x >> 3;
    int cnt = counts[e * 32];
    int base = tile * MT;
    if (base >= cnt) return;
    int rows = cnt - base; if (rows > MT) rows = MT;

    __shared__ __align__(16) ushort_t bufH[16384]; // 32KB: x chunks, h1, h2
    __shared__ int toks_s[MT];
    __shared__ float wts_s[MT];

    int tid = threadIdx.x;
    int lane = tid & 63;
    int w = tid >> 6;
    int q = lane >> 4;
    int mcol = lane & 15;

    const bf16x8* W1A = (const bf16x8*)(wt1f + (size_t)e * 4096 * 8);
    const bf16x8* W2A = (const bf16x8*)(wt2f + (size_t)e * 8192 * 8);
    const bf16x8* WoB = (const bf16x8*)wotf;
    const bf16x8* Hlbs = (const bf16x8*)bufH;

    if (tid < MT) {
        int rr = tid < rows ? tid : rows - 1;
        toks_s[tid] = list_tok[(size_t)e * N_TOK + base + rr];
        wts_s[tid] = list_w[(size_t)e * N_TOK + base + rr];
    }

    // prefetch GEMM1 A-frags (kstep 0) while staging runs
    bf16x8 a1r[2][4];
#pragma unroll
    for (int rtl = 0; rtl < 4; rtl++)
        a1r[0][rtl] = W1A[((w * 4 + rtl) * 4 + 0) * 64 + lane];

    // stage x tile (fp32 -> bf16) into chunk layout, row = fast index:
    // thread (tid) owns token row tid&63, kchunks (tid>>6)+4i.
    {
        int row = tid & 63;
        int rr = row < rows ? row : rows - 1;
        int tok = list_tok[(size_t)e * N_TOK + base + rr];
        const float* xrow = x + (size_t)tok * DIN;
#pragma unroll
        for (int i = 0; i < 4; i++) {
            int kchunk = (tid >> 6) + i * 4;   // kchunk>>2 == i, kchunk&3 == w
            const float4* src = (const float4*)(xrow + kchunk * 8);
            float4 lo = src[0], hi = src[1];
            unsigned p0, p1, p2, p3;
            asm("v_cvt_pk_bf16_f32 %0, %1, %2" : "=v"(p0) : "v"(lo.x), "v"(lo.y));
            asm("v_cvt_pk_bf16_f32 %0, %1, %2" : "=v"(p1) : "v"(lo.z), "v"(lo.w));
            asm("v_cvt_pk_bf16_f32 %0, %1, %2" : "=v"(p2) : "v"(hi.x), "v"(hi.y));
            asm("v_cvt_pk_bf16_f32 %0, %1, %2" : "=v"(p3) : "v"(hi.z), "v"(hi.w));
            int dchunk = (i * 4 + (row >> 4)) * 64 + (kchunk & 3) * 16 + (row & 15);
            u32x4 v; v.x = p0; v.y = p1; v.z = p2; v.w = p3;
            *(u32x4*)(&bufH[dchunk * 8]) = v;
        }
    }
    __syncthreads();

    // ---- GEMM1 (swapped): h1^T[n=256][t=64], wave w owns n rows w*64..+63
    f32x4 acc[4][4]; // [rtl][ct]
#pragma unroll
    for (int rtl = 0; rtl < 4; rtl++)
#pragma unroll
        for (int ct = 0; ct < 4; ct++) acc[rtl][ct] = (f32x4){0.f, 0.f, 0.f, 0.f};
#pragma unroll
    for (int ks = 0; ks < 4; ks++) {
        const int cur = ks & 1, nxt = cur ^ 1;
        if (ks < 3) {
#pragma unroll
            for (int rtl = 0; rtl < 4; rtl++)
                a1r[nxt][rtl] = W1A[((w * 4 + rtl) * 4 + ks + 1) * 64 + lane];
        }
        bf16x8 bf_[4];
#pragma unroll
        for (int ct = 0; ct < 4; ct++) bf_[ct] = Hlbs[(ks * 4 + ct) * 64 + lane];
#pragma unroll
        for (int rtl = 0; rtl < 4; rtl++)
#pragma unroll
            for (int ct = 0; ct < 4; ct++)
                acc[rtl][ct] = __builtin_amdgcn_mfma_f32_16x16x32_bf16(a1r[cur][rtl], bf_[ct], acc[rtl][ct], 0, 0, 0);
    }
    // prefetch GEMM2 A-frags (kstep 0); in flight across epilogue 1
    bf16x8 a2r[2][4];
#pragma unroll
    for (int rtl = 0; rtl < 4; rtl++)
        a2r[0][rtl] = W2A[((w * 4 + rtl) * 8 + 0) * 64 + lane];

    // JIT bias load (short live range; spills were the rounds-2/3 killer)
    float4 b1v[4];
#pragma unroll
    for (int rtl = 0; rtl < 4; rtl++)
        b1v[rtl] = *(const float4*)(b1 + e * HD + w * 64 + rtl * 16 + q * 4);

    __syncthreads(); // all waves done reading x chunks before h1 overwrite

    // epilogue 1: bias + relu -> h1 chunks (contiguous b64 stores)
#pragma unroll
    for (int rtl = 0; rtl < 4; rtl++) {
        int ks2 = w * 2 + (rtl >> 1);
        int q2 = (rtl * 2 + (q >> 1)) & 3;
        int uoff = (ks2 * 4 * 64 + q2 * 16 + mcol) * 8 + (q & 1) * 4;
#pragma unroll
        for (int ct = 0; ct < 4; ct++) {
            float v0 = acc[rtl][ct][0] + b1v[rtl].x; v0 = v0 > 0.f ? v0 : 0.f;
            float v1 = acc[rtl][ct][1] + b1v[rtl].y; v1 = v1 > 0.f ? v1 : 0.f;
            float v2 = acc[rtl][ct][2] + b1v[rtl].z; v2 = v2 > 0.f ? v2 : 0.f;
            float v3 = acc[rtl][ct][3] + b1v[rtl].w; v3 = v3 > 0.f ? v3 : 0.f;
            unsigned d0, d1;
            asm("v_cvt_pk_bf16_f32 %0, %1, %2" : "=v"(d0) : "v"(v0), "v"(v1));
            asm("v_cvt_pk_bf16_f32 %0, %1, %2" : "=v"(d1) : "v"(v2), "v"(v3));
            u32x2 dd; dd.x = d0; dd.y = d1;
            *(u32x2*)(&bufH[uoff + ct * 512]) = dd;
        }
    }
    __syncthreads();

    // ---- GEMM2 (swapped): h2^T = W2^T @ h1^T, K=256 ----
    f32x4 acc2[4][4];
#pragma unroll
    for (int rtl = 0; rtl < 4; rtl++)
#pragma unroll
        for (int ct = 0; ct < 4; ct++) acc2[rtl][ct] = (f32x4){0.f, 0.f, 0.f, 0.f};
#pragma unroll
    for (int ks = 0; ks < 8; ks++) {
        const int cur = ks & 1, nxt = cur ^ 1;
        if (ks < 7) {
#pragma unroll
            for (int rtl = 0; rtl < 4; rtl++)
                a2r[nxt][rtl] = W2A[((w * 4 + rtl) * 8 + ks + 1) * 64 + lane];
        }
        bf16x8 bf_[4];
#pragma unroll
        for (int ct = 0; ct < 4; ct++) bf_[ct] = Hlbs[(ks * 4 + ct) * 64 + lane];
#pragma unroll
        for (int rtl = 0; rtl < 4; rtl++)
#pragma unroll
            for (int ct = 0; ct < 4; ct++)
                acc2[rtl][ct] = __builtin_amdgcn_mfma_f32_16x16x32_bf16(a2r[cur][rtl], bf_[ct], acc2[rtl][ct], 0, 0, 0);
    }
    // prefetch GEMM3 B-frags (kstep 0); in flight across epilogue 2
    bf16x8 b3r[2][2];
#pragma unroll
    for (int nt = 0; nt < 2; nt++)
        b3r[0][nt] = WoB[((w * 2 + nt) * 8 + 0) * 64 + lane];

    // JIT bias load
    float4 b2v[4];
#pragma unroll
    for (int rtl = 0; rtl < 4; rtl++)
        b2v[rtl] = *(const float4*)(b2 + e * HD + w * 64 + rtl * 16 + q * 4);

    __syncthreads(); // all waves done reading h1 before h2 overwrite

    // epilogue 2: bias + relu -> h2 chunks
#pragma unroll
    for (int rtl = 0; rtl < 4; rtl++) {
        int ks2 = w * 2 + (rtl >> 1);
        int q2 = (rtl * 2 + (q >> 1)) & 3;
        int uoff = (ks2 * 4 * 64 + q2 * 16 + mcol) * 8 + (q & 1) * 4;
#pragma unroll
        for (int ct = 0; ct < 4; ct++) {
            float v0 = acc2[rtl][ct][0] + b2v[rtl].x; v0 = v0 > 0.f ? v0 : 0.f;
            float v1 = acc2[rtl][ct][1] + b2v[rtl].y; v1 = v1 > 0.f ? v1 : 0.f;
            float v2 = acc2[rtl][ct][2] + b2v[rtl].z; v2 = v2 > 0.f ? v2 : 0.f;
            float v3 = acc2[rtl][ct][3] + b2v[rtl].w; v3 = v3 > 0.f ? v3 : 0.f;
            unsigned d0, d1;
            asm("v_cvt_pk_bf16_f32 %0, %1, %2" : "=v"(d0) : "v"(v0), "v"(v1));
            asm("v_cvt_pk_bf16_f32 %0, %1, %2" : "=v"(d1) : "v"(v2), "v"(v3));
            u32x2 dd; dd.x = d0; dd.y = d1;
            *(u32x2*)(&bufH[uoff + ct * 512]) = dd;
        }
    }
    __syncthreads();

    // ---- GEMM3 (unswapped): y = h2 @ Wo; weighted atomic combine ----
    f32x4 acc3[4][2]; // [mt][nt]
#pragma unroll
    for (int mt = 0; mt < 4; mt++)
#pragma unroll
        for (int nt = 0; nt < 2; nt++) acc3[mt][nt] = (f32x4){0.f, 0.f, 0.f, 0.f};
#pragma unroll
    for (int ks = 0; ks < 8; ks++) {
        const int cur = ks & 1, nxt = cur ^ 1;
        if (ks < 7) {
#pragma unroll
            for (int nt = 0; nt < 2; nt++)
                b3r[nxt][nt] = WoB[((w * 2 + nt) * 8 + ks + 1) * 64 + lane];
        }
        bf16x8 af_[4];
#pragma unroll
        for (int mt = 0; mt < 4; mt++) af_[mt] = Hlbs[(ks * 4 + mt) * 64 + lane];
#pragma unroll
        for (int nt = 0; nt < 2; nt++)
#pragma unroll
            for (int mt = 0; mt < 4; mt++)
                acc3[mt][nt] = __builtin_amdgcn_mfma_f32_16x16x32_bf16(af_[mt], b3r[cur][nt], acc3[mt][nt], 0, 0, 0);
    }
#pragma unroll
    for (int mt = 0; mt < 4; mt++) {
#pragma unroll
        for (int r = 0; r < 4; r++) {
            int row = mt * 16 + q * 4 + r;
            if (row < rows) {
                int tok = toks_s[row];
                float wgt = wts_s[row];
                float* dst = out + (size_t)tok * DOUT;
#pragma unroll
                for (int nt = 0; nt < 2; nt++) {
                    int col = (w * 2 + nt) * 16 + mcol;
                    atomicAdd(&dst[col], wgt * acc3[mt][nt][r]);
                }
            }
        }
    }
}

extern "C" void kernel_launch(void* const* d_in, const int* in_sizes, int n_in,
                              void* d_out, int out_size, void* d_ws, size_t ws_size,
                              hipStream_t stream) {
    const float* x  = (const float*)d_in[0];
    const float* Wg = (const float*)d_in[1];
    const float* W1 = (const float*)d_in[2];
    const float* b1 = (const float*)d_in[3];
    const float* W2 = (const float*)d_in[4];
    const float* b2 = (const float*)d_in[5];
    const float* Wo = (const float*)d_in[6];
    const float* bo = (const float*)d_in[7];
    float* out = (float*)d_out;

    char* ws = (char*)d_ws;
    size_t off = 0;
    int* counts    = (int*)(ws + off);    off += 1024;  // 8 counters, 128B apart
    int* list_tok  = (int*)(ws + off);    off += (size_t)NEXP * N_TOK * 4;
    float* list_w  = (float*)(ws + off);  off += (size_t)NEXP * N_TOK * 4;
    ushort_t* wt1f = (ushort_t*)(ws + off); off += (size_t)NEXP * DIN * HD * 2;
    ushort_t* wt2f = (ushort_t*)(ws + off); off += (size_t)NEXP * HD * HD * 2;
    ushort_t* wotf = (ushort_t*)(ws + off); off += (size_t)HD * DOUT * 2;

    hipMemsetAsync(counts, 0, 1024, stream);
    router_kernel<<<N_TOK / RT_TPB, RT_BLOCK, 0, stream>>>(
        x, Wg, W1, W2, Wo, bo, counts, list_tok, list_w, wt1f, wt2f, wotf, out);
    expert_kernel<<<NEXP * MAX_TILES, 256, 0, stream>>>(x, counts, list_tok, list_w,
                                                        wt1f, wt2f, wotf, b1, b2, out);
}